// Round 19
// baseline (5193.535 us; speedup 1.0000x reference)
//
#include <hip/hip_runtime.h>

#define TT   1024
#define BB   64
#define DIN  256
#define HH   512
#define DOUT 256

#define NWG_L0  64
#define NWG_L1  128
#define NWG_OUT 8
#define NWG_TOT 200

typedef short bf16x8 __attribute__((ext_vector_type(8)));
typedef float f32x4  __attribute__((ext_vector_type(4)));
typedef unsigned u32x4 __attribute__((ext_vector_type(4)));

// x packed frags (cached path): f = (ks*4+ct)*64+lane, elem e
__device__ bf16x8 g_xf[TT * 2048];

// TAGGED h rings: u32 = value bf16 (hi16) | epoch tag (lo16); 8 slots.
// u32 index within slot: (ks*4 + ct)*512 + lane*8 + e  where
// value = h[k = ks*32+(lane>>4)*8+e][col = ct*16+(lane&15)]
#define SLOT_U32 (4 * 16 * 512)
__device__ unsigned g_h1t[8][SLOT_U32];
__device__ unsigned g_h2t[8][SLOT_U32];

// consumed-flags only (readiness is in-band via tags). R14 indices kept:
//   fc1L1[ct(4)][ub2(32)] : 192+  posts Qb+t+1 (consumed h1[t])
//   fc1L0[p(2)][ub(32)]   : 320+  posts Qb+t   (consumed h1[t-1])
//   fc2L1[ct(4)][ub2(32)] : 384+  posts Qb+t   (consumed h2[t-1])
//   fc2OUT[cp(2)*4+ob(4)] : 512+  posts Qb+t+1 (consumed h2[t])
// BP (every 4th step, t>=8, producers): all relevant fc >= Qb+t-4.
__device__ unsigned g_flg[520 * 16];
__device__ unsigned g_iter;

__device__ __forceinline__ unsigned* FLG(int idx) { return &g_flg[idx * 16]; }

// ---------- explicitly-coherent (IF-level) primitives: bypass L1+L2
__device__ __forceinline__ u32x4 ldg_cv16(const void* p) {
    u32x4 r;
    asm volatile("global_load_dwordx4 %0, %1, off sc0 sc1"
                 : "=&v"(r) : "v"(p) : "memory");
    return r;
}
__device__ __forceinline__ void stg_cv_u32(void* p, unsigned v) {
    asm volatile("global_store_dword %0, %1, off sc0 sc1" :: "v"(p), "v"(v) : "memory");
}
__device__ __forceinline__ void wait_vm0(void) {
    asm volatile("s_waitcnt vmcnt(0)" ::: "memory");
}

// ---------- lane-parallel flag wait (UNSIGNED compare; inactive lanes hold ~0)
__device__ __forceinline__ void waitpoll(const unsigned* p, unsigned tgt, int active, int tid) {
    for (;;) {
        unsigned v = 0xFFFFFFFFu;
        if (active)
            asm volatile("global_load_dword %0, %1, off sc0 sc1\n\t"
                         "s_waitcnt vmcnt(0)"
                         : "=&v"(v) : "v"(p) : "memory");
        if (__all(v >= tgt)) break;
        __builtin_amdgcn_s_sleep(1);
    }
    __syncthreads();
}

__device__ __forceinline__ int tagok(u32x4 a, u32x4 b, unsigned etag) {
    return (int)((a[0] & 0xFFFFu) == etag) & (int)((a[1] & 0xFFFFu) == etag)
         & (int)((a[2] & 0xFFFFu) == etag) & (int)((a[3] & 0xFFFFu) == etag)
         & (int)((b[0] & 0xFFFFu) == etag) & (int)((b[1] & 0xFFFFu) == etag)
         & (int)((b[2] & 0xFFFFu) == etag) & (int)((b[3] & 0xFFFFu) == etag);
}
__device__ __forceinline__ u32x4 untag(u32x4 a, u32x4 b) {   // 8 tagged dwords -> bf16x8
    u32x4 p;
    p[0] = (a[0] >> 16) | (a[1] & 0xFFFF0000u);
    p[1] = (a[2] >> 16) | (a[3] & 0xFFFF0000u);
    p[2] = (b[0] >> 16) | (b[1] & 0xFFFF0000u);
    p[3] = (b[2] >> 16) | (b[3] & 0xFFFF0000u);
    return p;
}

__device__ __forceinline__ float sigf(float v) { return 1.f / (1.f + __expf(-v)); }
__device__ __forceinline__ float tanh_fast(float v) { return 2.f / (1.f + __expf(-2.f * v)) - 1.f; }

__device__ __forceinline__ short f2bf(float f) {   // RNE float->bf16 bits
    unsigned u = __builtin_bit_cast(unsigned, f);
    unsigned r = (u + 0x7FFFu + ((u >> 16) & 1u)) >> 16;
    return (short)r;
}

__device__ __forceinline__ bf16x8 pack8(float4 v0, float4 v1) {
    bf16x8 r;
    r[0] = f2bf(v0.x); r[1] = f2bf(v0.y); r[2] = f2bf(v0.z); r[3] = f2bf(v0.w);
    r[4] = f2bf(v1.x); r[5] = f2bf(v1.y); r[6] = f2bf(v1.z); r[7] = f2bf(v1.w);
    return r;
}

// producer u32 index for value (unit j, batch b) — inverse of consumer layout
__device__ __forceinline__ int pidx_of(int j, int b) {
    return ((j >> 5) * 4 + (b >> 4)) * 512 + (((j >> 3) & 3) * 16 + (b & 15)) * 8 + (j & 7);
}

// ---------------- pre-pass: pack x (fp32 [T][B][DIN]) into frag-ordered bf16
extern "C" __global__ void __launch_bounds__(256)
pack_x(const float* __restrict__ x) {
    const int t = blockIdx.x, tid = threadIdx.x;
    const float* xt = x + (size_t)t * BB * DIN;
    bf16x8* dst = g_xf + (size_t)t * 2048;
    #pragma unroll
    for (int u = 0; u < 8; ++u) {
        const int f = u * 256 + tid;
        const int lane_ = f & 63, ctks = f >> 6;
        const int ct = ctks & 3, ks = ctks >> 2;
        const int b  = ct * 16 + (lane_ & 15);
        const int kb = ks * 32 + (lane_ >> 4) * 8;
        const float4* s = (const float4*)(xt + b * DIN + kb);
        dst[f] = pack8(s[0], s[1]);
    }
}

// ---------------- L0: 64 WGs (p=grp 0..1, ub 0..31); wave = 4 units, 2 quadrants
__device__ void run_l0(int lwg, int tid,
                       const float* __restrict__ wih, const float* __restrict__ whh,
                       const float* __restrict__ bih, const float* __restrict__ bhh,
                       float* __restrict__ out, unsigned Q, bf16x8* sB)
{
    constexpr int NKSA = 8, NKS = 24;
    const int lane = tid & 63, lo = lane & 15, hi = lane >> 4;
    const int w = tid >> 6;
    const int grp = lwg & 1, ub = lwg >> 1;
    const int ctbase = grp * 2;
    const int jbase = (ub * 4 + w) * 4;
    const int grow = (lo & 3) * HH + jbase + (lo >> 2);

    bf16x8 aF[NKS];
    #pragma unroll
    for (int ks = 0; ks < NKS; ++ks) {
        const float* wr = (ks < NKSA) ? wih + (size_t)grow * DIN + ks * 32 + hi * 8
                                      : whh + (size_t)grow * HH + (ks - NKSA) * 32 + hi * 8;
        const float4* p = (const float4*)wr;
        aF[ks] = pack8(p[0], p[1]);
    }
    f32x4 biasv;
    #pragma unroll
    for (int r = 0; r < 4; ++r)
        biasv[r] = bih[r * HH + jbase + hi] + bhh[r * HH + jbase + hi];

    const unsigned Qb = Q * 2048u;
    float cst[2] = {0.f, 0.f};

    for (int t = 0; t < TT; ++t) {
        __syncthreads();   // sB reuse fence (L0 rewrites all rows each step)

        // stage A: cached x rows (ri = r*4+w: ks=ri>>1, c=ri&1)
        u32x4 sa[4];
        #pragma unroll
        for (int r = 0; r < 4; ++r) {
            const int ri = r * 4 + w, ks = ri >> 1, c = ri & 1;
            sa[r] = *(const u32x4*)&g_xf[(size_t)t * 2048 + (ks * 4 + ctbase + c) * 64 + lane];
        }
        #pragma unroll
        for (int r = 0; r < 4; ++r)
            ((u32x4*)sB)[(r * 4 + w) * 64 + lane] = sa[r];

        // stage B: h1[t-1] tagged, poll-by-data
        if (t > 0) {
            const unsigned etag = (Qb + t) & 0xFFFFu;
            const unsigned* slot = g_h1t[(t - 1) & 7];
            u32x4 da[8], db[8];
            for (;;) {
                #pragma unroll
                for (int r = 0; r < 8; ++r) {
                    const int ri = r * 4 + w, ks = ri >> 1, c = ri & 1;
                    const unsigned* p = slot + (ks * 4 + ctbase + c) * 512 + lane * 8;
                    da[r] = ldg_cv16(p); db[r] = ldg_cv16(p + 4);
                }
                wait_vm0();
                int ok = 1;
                #pragma unroll
                for (int r = 0; r < 8; ++r) ok &= tagok(da[r], db[r], etag);
                if (__all(ok)) break;
                __builtin_amdgcn_s_sleep(1);
            }
            #pragma unroll
            for (int r = 0; r < 8; ++r)
                ((u32x4*)sB)[(16 + r * 4 + w) * 64 + lane] = untag(da[r], db[r]);
        }
        __syncthreads();
        if (tid == 0) stg_cv_u32(FLG(320 + grp * 32 + ub), Qb + t);   // consumed h1[t-1]

        // BP every 4th step (producers of h1 check h1 consumers)
        if (((t & 3) == 0) && t >= 8) {
            const unsigned* wp = g_flg; unsigned wt = 0; int wa = 0;
            if (w == 1) { wp = FLG(192 + (2 * grp + (lane >> 5)) * 32 + (lane & 31));
                          wt = Qb + t - 4; wa = 1; }
            else if (w == 2 && lane < 32) { wp = FLG(320 + grp * 32 + lane);
                                            wt = Qb + t - 4; wa = 1; }
            waitpoll(wp, wt, wa, tid);
        }

        f32x4 acc[2] = {biasv, biasv};
        #pragma unroll
        for (int ks = 0; ks < NKSA; ++ks)
            #pragma unroll
            for (int c = 0; c < 2; ++c)
                acc[c] = __builtin_amdgcn_mfma_f32_16x16x32_bf16(
                    aF[ks], sB[(ks * 2 + c) * 64 + lane], acc[c], 0, 0, 0);
        if (t > 0) {
            #pragma unroll
            for (int ks = NKSA; ks < NKS; ++ks)
                #pragma unroll
                for (int c = 0; c < 2; ++c)
                    acc[c] = __builtin_amdgcn_mfma_f32_16x16x32_bf16(
                        aF[ks], sB[(ks * 2 + c) * 64 + lane], acc[c], 0, 0, 0);
        }

        // act + tagged h1 store (fire-and-forget; no drain, no flag)
        const unsigned ptag = (Qb + t + 1) & 0xFFFFu;
        unsigned* slotW = g_h1t[t & 7];
        #pragma unroll
        for (int c = 0; c < 2; ++c) {
            const float gi = acc[c][0], gf = acc[c][1];
            const float gg = acc[c][2], go = acc[c][3];
            const float cn_ = sigf(gf) * cst[c] + sigf(gi) * tanh_fast(gg);
            const float hv  = sigf(go) * tanh_fast(cn_);
            cst[c] = cn_;
            const int j = jbase + hi, b = (ctbase + c) * 16 + lo;
            stg_cv_u32(slotW + pidx_of(j, b),
                       ((unsigned)(unsigned short)f2bf(hv) << 16) | ptag);
            if (t == TT - 1) {
                const size_t base = (size_t)TT * BB * DOUT;
                out[base + (size_t)b * HH + j] = hv;
                out[base + (size_t)2 * BB * HH + (size_t)b * HH + j] = cn_;
            }
        }
    }
}

// ---------------- L1: 128 WGs (ct=grp 0..3, ub2 0..31); wave = 4 units, 1 quadrant
__device__ void run_l1(int lwg, int tid,
                       const float* __restrict__ wih, const float* __restrict__ whh,
                       const float* __restrict__ bih, const float* __restrict__ bhh,
                       float* __restrict__ out, unsigned Q, bf16x8* sB)
{
    constexpr int NKSA = 16, NKS = 32;
    const int lane = tid & 63, lo = lane & 15, hi = lane >> 4;
    const int w = tid >> 6;
    const int grp = lwg & 3, ub = lwg >> 2;
    const int jbase = (ub * 4 + w) * 4;
    const int grow = (lo & 3) * HH + jbase + (lo >> 2);

    bf16x8 aF[NKS];
    #pragma unroll
    for (int ks = 0; ks < NKS; ++ks) {
        const float* wr = (ks < NKSA) ? wih + (size_t)grow * HH + ks * 32 + hi * 8
                                      : whh + (size_t)grow * HH + (ks - NKSA) * 32 + hi * 8;
        const float4* p = (const float4*)wr;
        aF[ks] = pack8(p[0], p[1]);
    }
    f32x4 biasv;
    #pragma unroll
    for (int r = 0; r < 4; ++r)
        biasv[r] = bih[r * HH + jbase + hi] + bhh[r * HH + jbase + hi];

    const unsigned Qb = Q * 2048u;
    float cst = 0.f;

    for (int t = 0; t < TT; ++t) {
        // ---- stage A = h1[t] tagged (rows 0..15; disjoint from B rows -> no top bar)
        {
            const unsigned etag = (Qb + t + 1) & 0xFFFFu;
            const unsigned* slot = g_h1t[t & 7];
            u32x4 da[4], db[4];
            for (;;) {
                #pragma unroll
                for (int r = 0; r < 4; ++r) {
                    const unsigned* p = slot + ((r * 4 + w) * 4 + grp) * 512 + lane * 8;
                    da[r] = ldg_cv16(p); db[r] = ldg_cv16(p + 4);
                }
                wait_vm0();
                int ok = 1;
                #pragma unroll
                for (int r = 0; r < 4; ++r) ok &= tagok(da[r], db[r], etag);
                if (__all(ok)) break;
                __builtin_amdgcn_s_sleep(1);
            }
            #pragma unroll
            for (int r = 0; r < 4; ++r)
                ((u32x4*)sB)[(r * 4 + w) * 64 + lane] = untag(da[r], db[r]);
        }
        __syncthreads();                                            // barrier 1
        if (tid == 0) stg_cv_u32(FLG(192 + grp * 32 + ub), Qb + t + 1);  // consumed h1[t]

        f32x4 acc = biasv;
        if (t > 0) {
            const unsigned etag = (Qb + t) & 0xFFFFu;
            const unsigned* slot = g_h2t[(t - 1) & 7];
            u32x4 da[4], db[4];
            #pragma unroll
            for (int r = 0; r < 4; ++r) {   // issue B loads, then hide under A-MFMAs
                const unsigned* p = slot + ((r * 4 + w) * 4 + grp) * 512 + lane * 8;
                da[r] = ldg_cv16(p); db[r] = ldg_cv16(p + 4);
            }
            #pragma unroll
            for (int ks = 0; ks < NKSA; ++ks)
                acc = __builtin_amdgcn_mfma_f32_16x16x32_bf16(
                    aF[ks], sB[ks * 64 + lane], acc, 0, 0, 0);
            for (;;) {
                wait_vm0();
                int ok = 1;
                #pragma unroll
                for (int r = 0; r < 4; ++r) ok &= tagok(da[r], db[r], etag);
                if (__all(ok)) break;
                __builtin_amdgcn_s_sleep(1);
                #pragma unroll
                for (int r = 0; r < 4; ++r) {
                    const unsigned* p = slot + ((r * 4 + w) * 4 + grp) * 512 + lane * 8;
                    da[r] = ldg_cv16(p); db[r] = ldg_cv16(p + 4);
                }
            }
            #pragma unroll
            for (int r = 0; r < 4; ++r)
                ((u32x4*)sB)[(16 + r * 4 + w) * 64 + lane] = untag(da[r], db[r]);
            __syncthreads();                                        // barrier 2
            if (tid == 0) stg_cv_u32(FLG(384 + grp * 32 + ub), Qb + t);  // consumed h2[t-1]
            #pragma unroll
            for (int ks = NKSA; ks < NKS; ++ks)
                acc = __builtin_amdgcn_mfma_f32_16x16x32_bf16(
                    aF[ks], sB[ks * 64 + lane], acc, 0, 0, 0);
        } else {
            #pragma unroll
            for (int ks = 0; ks < NKSA; ++ks)
                acc = __builtin_amdgcn_mfma_f32_16x16x32_bf16(
                    aF[ks], sB[ks * 64 + lane], acc, 0, 0, 0);
            __syncthreads();   // t=0: protect A rows from t=1's rewrites
            if (tid == 0) stg_cv_u32(FLG(384 + grp * 32 + ub), Qb);
        }

        // BP every 4th step (producers of h2 check h2 consumers)
        if (((t & 3) == 0) && t >= 8) {
            const unsigned* wp = g_flg; unsigned wt = 0; int wa = 0;
            if (w == 1) {
                if (lane < 32)      { wp = FLG(384 + grp * 32 + lane); wt = Qb + t - 4; wa = 1; }
                else if (lane < 36) { wp = FLG(512 + (grp >> 1) * 4 + (lane - 32));
                                      wt = Qb + t - 4; wa = 1; }
            }
            waitpoll(wp, wt, wa, tid);
        }

        // act + tagged h2 store
        const float gi = acc[0], gf = acc[1], gg = acc[2], go = acc[3];
        const float cn_ = sigf(gf) * cst + sigf(gi) * tanh_fast(gg);
        const float hv  = sigf(go) * tanh_fast(cn_);
        cst = cn_;
        const unsigned ptag = (Qb + t + 1) & 0xFFFFu;
        const int j = jbase + hi, b = grp * 16 + lo;
        stg_cv_u32(g_h2t[t & 7] + pidx_of(j, b),
                   ((unsigned)(unsigned short)f2bf(hv) << 16) | ptag);
        if (t == TT - 1) {
            const size_t base = (size_t)TT * BB * DOUT;
            out[base + (size_t)BB * HH + (size_t)b * HH + j] = hv;
            out[base + (size_t)3 * BB * HH + (size_t)b * HH + j] = cn_;
        }
    }
}

// ---------------- OUT: 8 WGs (cp 0..1, ob 0..3); wave = 16 odims, 2 quadrants
__device__ void run_out(int lwg, int tid,
                        const float* __restrict__ wout, const float* __restrict__ bout,
                        float* __restrict__ out, unsigned Q, bf16x8* sB)
{
    constexpr int NKS = HH / 32;   // 16
    const int lane = tid & 63, lo = lane & 15, hi = lane >> 4;
    const int w = tid >> 6;
    const int cp = lwg & 1, ob = lwg >> 1;
    const int ctbase = cp * 2;
    const int obase = (ob * 4 + w) * 16;
    const unsigned Qb = Q * 2048u;

    bf16x8 aF[NKS];
    #pragma unroll
    for (int ks = 0; ks < NKS; ++ks) {
        const float4* p = (const float4*)(wout + (size_t)(obase + lo) * HH + ks * 32 + hi * 8);
        aF[ks] = pack8(p[0], p[1]);
    }
    f32x4 biasv;
    #pragma unroll
    for (int r = 0; r < 4; ++r) biasv[r] = bout[obase + hi * 4 + r];

    for (int t = 0; t < TT; ++t) {
        __syncthreads();   // sB reuse fence
        {
            const unsigned etag = (Qb + t + 1) & 0xFFFFu;
            const unsigned* slot = g_h2t[t & 7];
            u32x4 da[8], db[8];
            for (;;) {
                #pragma unroll
                for (int r = 0; r < 8; ++r) {
                    const int ri = r * 4 + w, ks = ri >> 1, c = ri & 1;
                    const unsigned* p = slot + (ks * 4 + ctbase + c) * 512 + lane * 8;
                    da[r] = ldg_cv16(p); db[r] = ldg_cv16(p + 4);
                }
                wait_vm0();
                int ok = 1;
                #pragma unroll
                for (int r = 0; r < 8; ++r) ok &= tagok(da[r], db[r], etag);
                if (__all(ok)) break;
                __builtin_amdgcn_s_sleep(1);
            }
            #pragma unroll
            for (int r = 0; r < 8; ++r)
                ((u32x4*)sB)[(r * 4 + w) * 64 + lane] = untag(da[r], db[r]);
        }
        __syncthreads();
        if (tid == 0) stg_cv_u32(FLG(512 + cp * 4 + ob), Qb + t + 1);  // consumed h2[t]

        f32x4 acc[2] = {biasv, biasv};
        #pragma unroll
        for (int ks = 0; ks < NKS; ++ks)
            #pragma unroll
            for (int c = 0; c < 2; ++c)
                acc[c] = __builtin_amdgcn_mfma_f32_16x16x32_bf16(
                    aF[ks], sB[(ks * 2 + c) * 64 + lane], acc[c], 0, 0, 0);
        #pragma unroll
        for (int c = 0; c < 2; ++c)
            #pragma unroll
            for (int r = 0; r < 4; ++r) {
                const int b = (ctbase + c) * 16 + lo, o = obase + hi * 4 + r;
                out[(size_t)t * BB * DOUT + (size_t)b * DOUT + o] = acc[c][r];
            }
    }
}

extern "C" __global__ void __launch_bounds__(256, 1)
lstm2_fused(const float* __restrict__ x,
            const float* __restrict__ wih0, const float* __restrict__ whh0,
            const float* __restrict__ bih0, const float* __restrict__ bhh0,
            const float* __restrict__ wih1, const float* __restrict__ whh1,
            const float* __restrict__ bih1, const float* __restrict__ bhh1,
            const float* __restrict__ wout, const float* __restrict__ bout,
            float* __restrict__ out)
{
    __shared__ bf16x8 sB[3072];   // 48KB: L0 uses all; L1/OUT 32KB

    const int tid = threadIdx.x, wg = blockIdx.x;
    const unsigned Q = __hip_atomic_load(&g_iter, __ATOMIC_RELAXED, __HIP_MEMORY_SCOPE_AGENT);

    if (wg < NWG_L0)
        run_l0(wg, tid, wih0, whh0, bih0, bhh0, out, Q, sB);
    else if (wg < NWG_L0 + NWG_L1)
        run_l1(wg - NWG_L0, tid, wih1, whh1, bih1, bhh1, out, Q, sB);
    else
        run_out(wg - NWG_L0 - NWG_L1, tid, wout, bout, out, Q, sB);

    // wg0 (an L0 WG) exits only after the pipeline drained; all WGs read Q long ago.
    if (wg == 0 && tid == 0)
        __hip_atomic_store(&g_iter, Q + 1, __ATOMIC_RELAXED, __HIP_MEMORY_SCOPE_AGENT);
}

extern "C" void kernel_launch(void* const* d_in, const int* in_sizes, int n_in,
                              void* d_out, int out_size, void* d_ws, size_t ws_size,
                              hipStream_t stream) {
    const float* x    = (const float*)d_in[0];
    const float* wih0 = (const float*)d_in[1];
    const float* whh0 = (const float*)d_in[2];
    const float* bih0 = (const float*)d_in[3];
    const float* bhh0 = (const float*)d_in[4];
    const float* wih1 = (const float*)d_in[5];
    const float* whh1 = (const float*)d_in[6];
    const float* bih1 = (const float*)d_in[7];
    const float* bhh1 = (const float*)d_in[8];
    const float* wout = (const float*)d_in[9];
    const float* bout = (const float*)d_in[10];
    float* out = (float*)d_out;

    hipLaunchKernelGGL(pack_x, dim3(TT), dim3(256), 0, stream, x);
    hipLaunchKernelGGL(lstm2_fused, dim3(NWG_TOT), dim3(256), 0, stream,
                       x, wih0, whh0, bih0, bhh0, wih1, whh1, bih1, bhh1,
                       wout, bout, out);
}

// Round 20
// 3995.786 us; speedup vs baseline: 1.2998x; 1.2998x over previous
//
#include <hip/hip_runtime.h>

#define TT   1024
#define BB   64
#define DIN  256
#define HH   512
#define DOUT 256

#define NWG_L0  32
#define NWG_L1  64
#define NWG_OUT 4
#define NWG_TOT 100

typedef short bf16x8 __attribute__((ext_vector_type(8)));
typedef float f32x4  __attribute__((ext_vector_type(4)));
typedef unsigned u32x4 __attribute__((ext_vector_type(4)));

// frag-ordered bf16 tensors: index f = ((ks*4 + ct)*64 + lane), element e
// value = M[k = ks*32 + (lane>>4)*8 + e][col = ct*16 + (lane&15)]
__device__ bf16x8 g_xf[TT * 2048];     // x packed (static, cached path)
__device__ bf16x8 g_h1f[8][4096];      // h1 ring, 8 slots (coherent-bypass path)
__device__ bf16x8 g_h2f[8][4096];      // h2 ring, 8 slots

// flags: one 64B line per WG role, monotone V = Q*2048 + t(+1). 16-wide fan-in.
//   fp1  [p(2)][ub(16)]   : 0   + p*16+ub    L0 posts h1[t] ready   (Qb+t+1)
//   fp2  [ct(4)][ub(16)]  : 32  + ct*16+ub   L1 posts h2[t] ready   (Qb+t+1)
//   fc1L1[ct(4)][ub(16)]  : 96  + ct*16+ub   L1 consumed h1[t]      (Qb+t+1)
//   fc1L0[p(2)][ub(16)]   : 160 + p*16+ub    L0 consumed h1[t-1]    (Qb+t)
//   fc2L1[ct(4)][ub(16)]  : 192 + ct*16+ub   L1 consumed h2[t-1]    (Qb+t)
//   fc2OUT[o(4)]          : 256 + o          OUT consumed h2[t]     (Qb+t+1)
// BP: producers check every 4th step (t>=8, t%4==0), uniform target Qb+t-4
// (8-deep rings; covers writes t..t+3 overwriting slots t-8..t-5; desk-checked).
__device__ unsigned g_flg[260 * 16];
__device__ unsigned g_iter;

__device__ __forceinline__ unsigned* FLG(int idx) { return &g_flg[idx * 16]; }

// ---------- explicitly-coherent (IF-level) primitives: bypass L1+L2
__device__ __forceinline__ u32x4 ldg_cv16(const void* p) {
    u32x4 r;
    asm volatile("global_load_dwordx4 %0, %1, off sc0 sc1"
                 : "=&v"(r) : "v"(p) : "memory");
    return r;
}
__device__ __forceinline__ void stg_cv16(void* p, u32x4 v) {
    asm volatile("global_store_dwordx4 %0, %1, off sc0 sc1" :: "v"(p), "v"(v) : "memory");
}
__device__ __forceinline__ void stg_cv_u32(void* p, unsigned v) {
    asm volatile("global_store_dword %0, %1, off sc0 sc1" :: "v"(p), "v"(v) : "memory");
}
__device__ __forceinline__ void wait_vm0(void) {
    asm volatile("s_waitcnt vmcnt(0)" ::: "memory");
}

// ---------- lane-parallel flag wait (UNSIGNED compare; inactive lanes hold ~0)
__device__ __forceinline__ void waitpoll(const unsigned* p, unsigned tgt, int active, int tid) {
    for (;;) {
        unsigned v = 0xFFFFFFFFu;
        if (active)
            asm volatile("global_load_dword %0, %1, off sc0 sc1\n\t"
                         "s_waitcnt vmcnt(0)"
                         : "=&v"(v) : "v"(p) : "memory");
        if (__all(v >= tgt)) break;
        __builtin_amdgcn_s_sleep(1);
    }
    __syncthreads();
}

__device__ __forceinline__ float sigf(float v) { return 1.f / (1.f + __expf(-v)); }
__device__ __forceinline__ float tanh_fast(float v) { return 2.f / (1.f + __expf(-2.f * v)) - 1.f; }

__device__ __forceinline__ short f2bf(float f) {   // RNE float->bf16 bits
    unsigned u = __builtin_bit_cast(unsigned, f);
    unsigned r = (u + 0x7FFFu + ((u >> 16) & 1u)) >> 16;
    return (short)r;
}

__device__ __forceinline__ bf16x8 pack8(float4 v0, float4 v1) {
    bf16x8 r;
    r[0] = f2bf(v0.x); r[1] = f2bf(v0.y); r[2] = f2bf(v0.z); r[3] = f2bf(v0.w);
    r[4] = f2bf(v1.x); r[5] = f2bf(v1.y); r[6] = f2bf(v1.z); r[7] = f2bf(v1.w);
    return r;
}

// ---------------- pre-pass: pack x (fp32 [T][B][DIN]) into frag-ordered bf16
extern "C" __global__ void __launch_bounds__(256)
pack_x(const float* __restrict__ x) {
    const int t = blockIdx.x, tid = threadIdx.x;
    const float* xt = x + (size_t)t * BB * DIN;
    bf16x8* dst = g_xf + (size_t)t * 2048;
    #pragma unroll
    for (int u = 0; u < 8; ++u) {
        const int f = u * 256 + tid;
        const int lane_ = f & 63, ctks = f >> 6;
        const int ct = ctks & 3, ks = ctks >> 2;
        const int b  = ct * 16 + (lane_ & 15);
        const int kb = ks * 32 + (lane_ >> 4) * 8;
        const float4* s = (const float4*)(xt + b * DIN + kb);
        dst[f] = pack8(s[0], s[1]);
    }
}

// ---------------- L0: 32 WGs (p 0..1, ub 0..15) x 512 thr; wave w 0..7 owns 4 units.
// WG owns units ub*32..+31 x quadrants 2p,2p+1. A = x (cached), B = h1[t-1] (bypass).
__device__ void run_l0(int lwg, int tid,
                       const float* __restrict__ wih, const float* __restrict__ whh,
                       const float* __restrict__ bih, const float* __restrict__ bhh,
                       float* __restrict__ out, unsigned Q, bf16x8* sB, short* sH)
{
    constexpr int NKSA = 8, NKS = 24;
    const int lane = tid & 63, lo = lane & 15, hi = lane >> 4;
    const int w = tid >> 6;
    const int grp = lwg & 1, ub = lwg >> 1;
    const int ctbase = grp * 2;
    const int jbase = ub * 32 + w * 4;
    const int grow = (lo & 3) * HH + jbase + (lo >> 2);

    bf16x8 aF[NKS];
    #pragma unroll
    for (int ks = 0; ks < NKS; ++ks) {
        const float* wr = (ks < NKSA) ? wih + (size_t)grow * DIN + ks * 32 + hi * 8
                                      : whh + (size_t)grow * HH + (ks - NKSA) * 32 + hi * 8;
        const float4* p = (const float4*)wr;
        aF[ks] = pack8(p[0], p[1]);
    }
    f32x4 biasv;
    #pragma unroll
    for (int r = 0; r < 4; ++r)
        biasv[r] = bih[r * HH + jbase + hi] + bhh[r * HH + jbase + hi];

    const unsigned Qb = Q * 2048u;
    float cst[2] = {0.f, 0.f};

    for (int t = 0; t < TT; ++t) {
        // ---- front poll: h1[t-1] ready (w0, 16 lanes) + amortized BP (w1, 48 lanes)
        {
            const unsigned* wp = g_flg; unsigned wt = 0; int wa = 0;
            const int bp = (t >= 8) && ((t & 3) == 0);
            if (w == 0) { if (lane < 16 && t >= 1) { wp = FLG(0 + grp * 16 + lane);
                                                     wt = Qb + t; wa = 1; } }
            else if (w == 1 && bp) {
                if (lane < 32)      { wp = FLG(96 + (2 * grp + (lane >> 4)) * 16 + (lane & 15));
                                      wt = Qb + t - 4; wa = 1; }
                else if (lane < 48) { wp = FLG(160 + grp * 16 + (lane - 32));
                                      wt = Qb + t - 4; wa = 1; }
            }
            waitpoll(wp, wt, wa, tid);   // syncthreads = sB/sH reuse fence
        }

        // ---- stage 48 rows (6/wave): ri<16 A-cached, else B-bypass; sB row = ri
        const bf16x8* srcA = g_xf + (size_t)t * 2048;
        const bf16x8* srcB = g_h1f[(t - 1) & 7];
        u32x4 stg[6];
        #pragma unroll
        for (int r = 0; r < 6; ++r) {
            const int ri = r * 8 + w;
            if (ri < 16) {
                const int ks = ri >> 1, c = ri & 1;
                stg[r] = *(const u32x4*)&srcA[(ks * 4 + ctbase + c) * 64 + lane];
            } else if (t > 0) {
                const int ks = (ri - 16) >> 1, c = (ri - 16) & 1;
                stg[r] = ldg_cv16(&srcB[(ks * 4 + ctbase + c) * 64 + lane]);
            }
        }
        wait_vm0();
        #pragma unroll
        for (int r = 0; r < 6; ++r)
            ((u32x4*)sB)[(r * 8 + w) * 64 + lane] = stg[r];
        __syncthreads();
        if (tid == 0) stg_cv_u32(FLG(160 + grp * 16 + ub), Qb + t);   // consumed h1[t-1]

        f32x4 acc[2] = {biasv, biasv};
        #pragma unroll
        for (int ks = 0; ks < NKSA; ++ks)
            #pragma unroll
            for (int c = 0; c < 2; ++c)
                acc[c] = __builtin_amdgcn_mfma_f32_16x16x32_bf16(
                    aF[ks], sB[(ks * 2 + c) * 64 + lane], acc[c], 0, 0, 0);
        if (t > 0) {
            #pragma unroll
            for (int ks = NKSA; ks < NKS; ++ks)
                #pragma unroll
                for (int c = 0; c < 2; ++c)
                    acc[c] = __builtin_amdgcn_mfma_f32_16x16x32_bf16(
                        aF[ks], sB[(ks * 2 + c) * 64 + lane], acc[c], 0, 0, 0);
        }

        // ---- act; pack sH[c][lane'][e]: j' = w*4+hi, lane' = (j'>>3)*16+lo, e = j'&7
        #pragma unroll
        for (int c = 0; c < 2; ++c) {
            const float gi = acc[c][0], gf = acc[c][1];
            const float gg = acc[c][2], go = acc[c][3];
            const float cn_ = sigf(gf) * cst[c] + sigf(gi) * tanh_fast(gg);
            const float hv  = sigf(go) * tanh_fast(cn_);
            cst[c] = cn_;
            const int jp = w * 4 + hi;
            sH[(c * 64 + (jp >> 3) * 16 + lo) * 8 + (jp & 7)] = f2bf(hv);
            if (t == TT - 1) {
                const int j = jbase + hi, b = (ctbase + c) * 16 + lo;
                const size_t base = (size_t)TT * BB * DOUT;
                out[base + (size_t)b * HH + j] = hv;
                out[base + (size_t)2 * BB * HH + (size_t)b * HH + j] = cn_;
            }
        }
        __syncthreads();   // publish sH to wave0

        // ---- wave0: 2 full 1KB rows (2 x 16B per lane), drain, post ready
        u32x4* ringW = (u32x4*)g_h1f[t & 7];
        if (tid < 64) {
            #pragma unroll
            for (int c = 0; c < 2; ++c)
                stg_cv16(ringW + (ub * 4 + ctbase + c) * 64 + tid,
                         *(const u32x4*)&sH[(c * 64 + tid) * 8]);
        }
        wait_vm0();
        if (tid == 0) stg_cv_u32(FLG(0 + grp * 16 + ub), Qb + t + 1);
    }
}

// ---------------- L1: 64 WGs (ct 0..3, ub 0..15) x 512 thr; wave owns 4 units.
// Split-phase: stage A(h1[t]) -> critical h2 poll -> B-loads || A-MFMAs.
__device__ void run_l1(int lwg, int tid,
                       const float* __restrict__ wih, const float* __restrict__ whh,
                       const float* __restrict__ bih, const float* __restrict__ bhh,
                       float* __restrict__ out, unsigned Q, bf16x8* sB, short* sH)
{
    constexpr int NKSA = 16, NKS = 32;
    const int lane = tid & 63, lo = lane & 15, hi = lane >> 4;
    const int w = tid >> 6;
    const int grp = lwg & 3, ub = lwg >> 2;
    const int jbase = ub * 32 + w * 4;
    const int grow = (lo & 3) * HH + jbase + (lo >> 2);

    bf16x8 aF[NKS];
    #pragma unroll
    for (int ks = 0; ks < NKS; ++ks) {
        const float* wr = (ks < NKSA) ? wih + (size_t)grow * HH + ks * 32 + hi * 8
                                      : whh + (size_t)grow * HH + (ks - NKSA) * 32 + hi * 8;
        const float4* p = (const float4*)wr;
        aF[ks] = pack8(p[0], p[1]);
    }
    f32x4 biasv;
    #pragma unroll
    for (int r = 0; r < 4; ++r)
        biasv[r] = bih[r * HH + jbase + hi] + bhh[r * HH + jbase + hi];

    const unsigned Qb = Q * 2048u;
    float cst = 0.f;

    for (int t = 0; t < TT; ++t) {
        // ---- phase-A gate: h1[t] ready (w0, 16 lanes) + amortized BP (w1, 18 lanes)
        {
            const unsigned* wp = g_flg; unsigned wt = 0; int wa = 0;
            const int bp = (t >= 8) && ((t & 3) == 0);
            if (w == 0) { if (lane < 16) { wp = FLG(0 + (grp >> 1) * 16 + lane);
                                           wt = Qb + t + 1; wa = 1; } }
            else if (w == 1 && bp) {
                if (lane < 16)      { wp = FLG(192 + grp * 16 + lane);
                                      wt = Qb + t - 4; wa = 1; }
                else if (lane < 18) { wp = FLG(256 + 2 * (grp >> 1) + (lane - 16));
                                      wt = Qb + t - 4; wa = 1; }
            }
            waitpoll(wp, wt, wa, tid);   // syncthreads = sB/sH reuse fence
        }

        // ---- stage A = h1[t] (2 rows/wave -> sB rows 0..15)
        const bf16x8* srcA = g_h1f[t & 7];
        u32x4 sa[2];
        #pragma unroll
        for (int r = 0; r < 2; ++r) {
            const int ks = r * 8 + w;
            sa[r] = ldg_cv16(&srcA[(ks * 4 + grp) * 64 + lane]);
        }
        wait_vm0();
        #pragma unroll
        for (int r = 0; r < 2; ++r)
            ((u32x4*)sB)[(r * 8 + w) * 64 + lane] = sa[r];
        __syncthreads();
        if (tid == 0) stg_cv_u32(FLG(96 + grp * 16 + ub), Qb + t + 1);   // consumed h1[t]

        // ---- critical poll: h2[t-1] ready (w0, 16 lanes)
        {
            const unsigned* wp = g_flg; unsigned wt = 0; int wa = 0;
            if (w == 0 && lane < 16 && t >= 1) { wp = FLG(32 + grp * 16 + lane);
                                                 wt = Qb + t; wa = 1; }
            waitpoll(wp, wt, wa, tid);
        }

        f32x4 acc = biasv;
        if (t > 0) {
            // B loads (2/wave) issued first, hidden under A-MFMAs
            const bf16x8* srcB = g_h2f[(t - 1) & 7];
            u32x4 sb[2];
            #pragma unroll
            for (int r = 0; r < 2; ++r) {
                const int ks = r * 8 + w;
                sb[r] = ldg_cv16(&srcB[(ks * 4 + grp) * 64 + lane]);
            }
            #pragma unroll
            for (int ks = 0; ks < NKSA; ++ks)
                acc = __builtin_amdgcn_mfma_f32_16x16x32_bf16(
                    aF[ks], sB[ks * 64 + lane], acc, 0, 0, 0);
            wait_vm0();
            #pragma unroll
            for (int r = 0; r < 2; ++r)
                ((u32x4*)sB)[(16 + r * 8 + w) * 64 + lane] = sb[r];
            __syncthreads();
            if (tid == 0) stg_cv_u32(FLG(192 + grp * 16 + ub), Qb + t);  // consumed h2[t-1]
            #pragma unroll
            for (int ks = NKSA; ks < NKS; ++ks)
                acc = __builtin_amdgcn_mfma_f32_16x16x32_bf16(
                    aF[ks], sB[ks * 64 + lane], acc, 0, 0, 0);
        } else {
            #pragma unroll
            for (int ks = 0; ks < NKSA; ++ks)
                acc = __builtin_amdgcn_mfma_f32_16x16x32_bf16(
                    aF[ks], sB[ks * 64 + lane], acc, 0, 0, 0);
            if (tid == 0) stg_cv_u32(FLG(192 + grp * 16 + ub), Qb);
        }

        // ---- act + sH pack (one h value per lane)
        {
            const float gi = acc[0], gf = acc[1], gg = acc[2], go = acc[3];
            const float cn_ = sigf(gf) * cst + sigf(gi) * tanh_fast(gg);
            const float hv  = sigf(go) * tanh_fast(cn_);
            cst = cn_;
            const int jp = w * 4 + hi;
            sH[((jp >> 3) * 16 + lo) * 8 + (jp & 7)] = f2bf(hv);
            if (t == TT - 1) {
                const int j = jbase + hi, b = grp * 16 + lo;
                const size_t base = (size_t)TT * BB * DOUT;
                out[base + (size_t)BB * HH + (size_t)b * HH + j] = hv;
                out[base + (size_t)3 * BB * HH + (size_t)b * HH + j] = cn_;
            }
        }
        __syncthreads();

        // ---- wave0: one full 1KB row, drain, post ready
        u32x4* ringW = (u32x4*)g_h2f[t & 7];
        if (tid < 64)
            stg_cv16(ringW + (ub * 4 + grp) * 64 + tid, *(const u32x4*)&sH[tid * 8]);
        wait_vm0();
        if (tid == 0) stg_cv_u32(FLG(32 + grp * 16 + ub), Qb + t + 1);
    }
}

// ---------------- OUT: 4 WGs (o 0..3: cp=o>>1, ob=o&1) x 512 thr; wave = 16 odims
__device__ void run_out(int o, int tid,
                        const float* __restrict__ wout, const float* __restrict__ bout,
                        float* __restrict__ out, unsigned Q, bf16x8* sB)
{
    constexpr int NKS = HH / 32;   // 16
    const int lane = tid & 63, lo = lane & 15, hi = lane >> 4;
    const int w = tid >> 6;
    const int cp = o >> 1, ob = o & 1;
    const int ctbase = cp * 2;
    const int obase = ob * 128 + w * 16;
    const unsigned Qb = Q * 2048u;

    bf16x8 aF[NKS];
    #pragma unroll
    for (int ks = 0; ks < NKS; ++ks) {
        const float4* p = (const float4*)(wout + (size_t)(obase + lo) * HH + ks * 32 + hi * 8);
        aF[ks] = pack8(p[0], p[1]);
    }
    f32x4 biasv;
    #pragma unroll
    for (int r = 0; r < 4; ++r) biasv[r] = bout[obase + hi * 4 + r];

    for (int t = 0; t < TT; ++t) {
        {   // h2[t] ready: 32 producer flags (two quadrants x 16)
            const unsigned* wp = g_flg; unsigned wt = 0; int wa = 0;
            if (w == 0 && lane < 32) {
                wp = FLG(32 + (ctbase + (lane >> 4)) * 16 + (lane & 15));
                wt = Qb + t + 1; wa = 1;
            }
            waitpoll(wp, wt, wa, tid);   // syncthreads = sB reuse fence
        }
        const bf16x8* src = g_h2f[t & 7];
        u32x4 stg[4];
        #pragma unroll
        for (int r = 0; r < 4; ++r) {
            const int ri = r * 8 + w, ks = ri >> 1, c = ri & 1;
            stg[r] = ldg_cv16(&src[(ks * 4 + ctbase + c) * 64 + lane]);
        }
        wait_vm0();
        #pragma unroll
        for (int r = 0; r < 4; ++r)
            ((u32x4*)sB)[(r * 8 + w) * 64 + lane] = stg[r];
        __syncthreads();
        if (tid == 0) stg_cv_u32(FLG(256 + o), Qb + t + 1);

        f32x4 acc[2] = {biasv, biasv};
        #pragma unroll
        for (int ks = 0; ks < NKS; ++ks)
            #pragma unroll
            for (int c = 0; c < 2; ++c)
                acc[c] = __builtin_amdgcn_mfma_f32_16x16x32_bf16(
                    aF[ks], sB[(ks * 2 + c) * 64 + lane], acc[c], 0, 0, 0);
        #pragma unroll
        for (int c = 0; c < 2; ++c)
            #pragma unroll
            for (int r = 0; r < 4; ++r) {
                const int b = (ctbase + c) * 16 + lo, oo = obase + hi * 4 + r;
                out[(size_t)t * BB * DOUT + (size_t)b * DOUT + oo] = acc[c][r];
            }
    }
}

extern "C" __global__ void __launch_bounds__(512, 1)
lstm2_fused(const float* __restrict__ x,
            const float* __restrict__ wih0, const float* __restrict__ whh0,
            const float* __restrict__ bih0, const float* __restrict__ bhh0,
            const float* __restrict__ wih1, const float* __restrict__ whh1,
            const float* __restrict__ bih1, const float* __restrict__ bhh1,
            const float* __restrict__ wout, const float* __restrict__ bout,
            float* __restrict__ out)
{
    __shared__ bf16x8 sB[3072];                     // 48KB: L0 uses all; L1/OUT 32KB
    __shared__ __align__(16) short sH[2 * 64 * 8];  // 2KB h-pack

    const int tid = threadIdx.x, wg = blockIdx.x;
    const unsigned Q = __hip_atomic_load(&g_iter, __ATOMIC_RELAXED, __HIP_MEMORY_SCOPE_AGENT);

    if (wg < NWG_L0)
        run_l0(wg, tid, wih0, whh0, bih0, bhh0, out, Q, sB, sH);
    else if (wg < NWG_L0 + NWG_L1)
        run_l1(wg - NWG_L0, tid, wih1, whh1, bih1, bhh1, out, Q, sB, sH);
    else
        run_out(wg - NWG_L0 - NWG_L1, tid, wout, bout, out, Q, sB);

    // wg0 (an L0 WG) exits only after the pipeline drained; all WGs read Q long ago.
    if (wg == 0 && tid == 0)
        __hip_atomic_store(&g_iter, Q + 1, __ATOMIC_RELAXED, __HIP_MEMORY_SCOPE_AGENT);
}

extern "C" void kernel_launch(void* const* d_in, const int* in_sizes, int n_in,
                              void* d_out, int out_size, void* d_ws, size_t ws_size,
                              hipStream_t stream) {
    const float* x    = (const float*)d_in[0];
    const float* wih0 = (const float*)d_in[1];
    const float* whh0 = (const float*)d_in[2];
    const float* bih0 = (const float*)d_in[3];
    const float* bhh0 = (const float*)d_in[4];
    const float* wih1 = (const float*)d_in[5];
    const float* whh1 = (const float*)d_in[6];
    const float* bih1 = (const float*)d_in[7];
    const float* bhh1 = (const float*)d_in[8];
    const float* wout = (const float*)d_in[9];
    const float* bout = (const float*)d_in[10];
    float* out = (float*)d_out;

    hipLaunchKernelGGL(pack_x, dim3(TT), dim3(256), 0, stream, x);
    hipLaunchKernelGGL(lstm2_fused, dim3(NWG_TOT), dim3(512), 0, stream,
                       x, wih0, whh0, bih0, bhh0, wih1, whh1, bih1, bhh1,
                       wout, bout, out);
}

// Round 22
// 3814.047 us; speedup vs baseline: 1.3617x; 1.0476x over previous
//
#include <hip/hip_runtime.h>

#define TT   1024
#define BB   64
#define DIN  256
#define HH   512
#define DOUT 256

#define NWG_L0  64
#define NWG_L1  128
#define NWG_OUT 8
#define NWG_TOT 200

typedef short bf16x8 __attribute__((ext_vector_type(8)));
typedef float f32x4  __attribute__((ext_vector_type(4)));
typedef unsigned u32x4 __attribute__((ext_vector_type(4)));

// frag-ordered bf16 tensors: index f = ((ks*4 + ct)*64 + lane), element e
// value = M[k = ks*32 + (lane>>4)*8 + e][col = ct*16 + (lane&15)]
__device__ bf16x8 g_xf[TT * 2048];     // x packed (static, cached path)
__device__ bf16x8 g_h1f[4][4096];      // h1 ring, 4 slots (coherent-bypass path)
__device__ bf16x8 g_h2f[4][4096];      // h2 ring
__device__ bf16x8 g_h1z[4096];         // t=-1 zeros (never written)
__device__ bf16x8 g_h2z[4096];

// per-WG progress flags, one 64B line each, monotone V = Q*2048 + t(+1). R14/R15 layout:
//   fp1  [p(2)][ub(32)]   : 0   + p*32+ub    L0 posts h1[t] ready    (Qb+t+1)
//   fp2  [ct(4)][ub2(32)] : 64  + ct*32+ub2  L1 posts h2[t] ready    (Qb+t+1)
//   fc1L1[ct(4)][ub2(32)] : 192 + ct*32+ub2  L1 consumed h1[t]       (Qb+t+1)
//   fc1L0[p(2)][ub(32)]   : 320 + p*32+ub    L0 consumed h1[t-1]     (Qb+t)
//   fc2L1[ct(4)][ub2(32)] : 384 + ct*32+ub2  L1 consumed h2[t-1]     (Qb+t)
//   fc2OUT[cp(2)*4+ob(4)] : 512 + cp*4+ob    OUT consumed h2[t]      (Qb+t+1)
__device__ unsigned g_flg[520 * 16];
__device__ unsigned g_iter;

__device__ __forceinline__ unsigned* FLG(int idx) { return &g_flg[idx * 16]; }

// ---------- explicitly-coherent (IF-level) primitives: bypass L1+L2
__device__ __forceinline__ u32x4 ldg_cv16(const void* p) {
    u32x4 r;
    asm volatile("global_load_dwordx4 %0, %1, off sc0 sc1"
                 : "=&v"(r) : "v"(p) : "memory");
    return r;
}
__device__ __forceinline__ void stg_cv16(void* p, u32x4 v) {
    asm volatile("global_store_dwordx4 %0, %1, off sc0 sc1" :: "v"(p), "v"(v) : "memory");
}
__device__ __forceinline__ void stg_cv_u32(void* p, unsigned v) {
    asm volatile("global_store_dword %0, %1, off sc0 sc1" :: "v"(p), "v"(v) : "memory");
}
__device__ __forceinline__ void wait_vm0(void) {
    asm volatile("s_waitcnt vmcnt(0)" ::: "memory");
}

// ---------- lane-parallel flag wait (UNSIGNED compare; inactive lanes hold ~0)
__device__ __forceinline__ void waitpoll(const unsigned* p, unsigned tgt, int active, int tid) {
    for (;;) {
        unsigned v = 0xFFFFFFFFu;
        if (active)
            asm volatile("global_load_dword %0, %1, off sc0 sc1\n\t"
                         "s_waitcnt vmcnt(0)"
                         : "=&v"(v) : "v"(p) : "memory");
        if (__all(v >= tgt)) break;
        __builtin_amdgcn_s_sleep(1);
    }
    __syncthreads();
}

__device__ __forceinline__ float sigf(float v) { return 1.f / (1.f + __expf(-v)); }
__device__ __forceinline__ float tanh_fast(float v) { return 2.f / (1.f + __expf(-2.f * v)) - 1.f; }

__device__ __forceinline__ short f2bf(float f) {   // RNE float->bf16 bits
    unsigned u = __builtin_bit_cast(unsigned, f);
    unsigned r = (u + 0x7FFFu + ((u >> 16) & 1u)) >> 16;
    return (short)r;
}

__device__ __forceinline__ bf16x8 pack8(float4 v0, float4 v1) {
    bf16x8 r;
    r[0] = f2bf(v0.x); r[1] = f2bf(v0.y); r[2] = f2bf(v0.z); r[3] = f2bf(v0.w);
    r[4] = f2bf(v1.x); r[5] = f2bf(v1.y); r[6] = f2bf(v1.z); r[7] = f2bf(v1.w);
    return r;
}

// ---------------- pre-pass: pack x (fp32 [T][B][DIN]) into frag-ordered bf16
extern "C" __global__ void __launch_bounds__(256)
pack_x(const float* __restrict__ x) {
    const int t = blockIdx.x, tid = threadIdx.x;
    const float* xt = x + (size_t)t * BB * DIN;
    bf16x8* dst = g_xf + (size_t)t * 2048;
    #pragma unroll
    for (int u = 0; u < 8; ++u) {
        const int f = u * 256 + tid;
        const int lane_ = f & 63, ctks = f >> 6;
        const int ct = ctks & 3, ks = ctks >> 2;
        const int b  = ct * 16 + (lane_ & 15);
        const int kb = ks * 32 + (lane_ >> 4) * 8;
        const float4* s = (const float4*)(xt + b * DIN + kb);
        dst[f] = pack8(s[0], s[1]);
    }
}

// ---------------- L0: 64 WGs (p=grp 0..1, ub 0..31); wave = 4 units, 2 quadrants.
// R15-proven split-phase: stage A (cached x) -> recurrent gate -> B-loads || A-MFMAs.
__device__ void run_l0(int lwg, int tid,
                       const float* __restrict__ wih, const float* __restrict__ whh,
                       const float* __restrict__ bih, const float* __restrict__ bhh,
                       float* __restrict__ out, unsigned Q, bf16x8* sB, short* sH)
{
    constexpr int NKSA = 8, NKS = 24;
    const int lane = tid & 63, lo = lane & 15, hi = lane >> 4;
    const int w = tid >> 6;
    const int grp = lwg & 1, ub = lwg >> 1;
    const int ctbase = grp * 2;
    const int jbase = (ub * 4 + w) * 4;
    const int grow = (lo & 3) * HH + jbase + (lo >> 2);

    bf16x8 aF[NKS];
    #pragma unroll
    for (int ks = 0; ks < NKS; ++ks) {
        const float* wr = (ks < NKSA) ? wih + (size_t)grow * DIN + ks * 32 + hi * 8
                                      : whh + (size_t)grow * HH + (ks - NKSA) * 32 + hi * 8;
        const float4* p = (const float4*)wr;
        aF[ks] = pack8(p[0], p[1]);
    }
    f32x4 biasv;
    #pragma unroll
    for (int r = 0; r < 4; ++r)
        biasv[r] = bih[r * HH + jbase + hi] + bhh[r * HH + jbase + hi];

    const unsigned Qb = Q * 2048u;
    float cst[2] = {0.f, 0.f};

    for (int t = 0; t < TT; ++t) {
        const bf16x8* srcA = g_xf + (size_t)t * 2048;
        const bf16x8* srcB = (t == 0) ? g_h1z : g_h1f[(t - 1) & 3];

        // ---- stage A (cached x): 4 rows/wave
        u32x4 stgA[4];
        #pragma unroll
        for (int r = 0; r < 4; ++r) {
            const int ri = r * 4 + w, ks = ri >> 1, c = ri & 1;
            stgA[r] = *(const u32x4*)&srcA[(ks * 4 + ctbase + c) * 64 + lane];
        }
        wait_vm0();
        #pragma unroll
        for (int r = 0; r < 4; ++r)
            ((u32x4*)sB)[(r * 4 + w) * 64 + lane] = stgA[r];

        // ---- recurrent gate: h1[t-1] ready (trailing sync also publishes A in LDS)
        {
            const unsigned* wp = g_flg; unsigned wt = 0; int wa = 0;
            if (w == 0 && lane < 32 && t >= 1) { wp = FLG(0 + grp * 32 + lane);
                                                 wt = Qb + t; wa = 1; }
            waitpoll(wp, wt, wa, tid);
        }

        // ---- B loads (8 rows/wave) issued first, hidden under A-MFMAs
        u32x4 stgB[8];
        #pragma unroll
        for (int r = 0; r < 8; ++r) {
            const int ri = r * 4 + w, ks = ri >> 1, c = ri & 1;
            stgB[r] = ldg_cv16(&srcB[(ks * 4 + ctbase + c) * 64 + lane]);
        }
        f32x4 acc[2] = {biasv, biasv};
        #pragma unroll
        for (int ks = 0; ks < NKSA; ++ks)
            #pragma unroll
            for (int c = 0; c < 2; ++c)
                acc[c] = __builtin_amdgcn_mfma_f32_16x16x32_bf16(
                    aF[ks], sB[(ks * 2 + c) * 64 + lane], acc[c], 0, 0, 0);
        wait_vm0();
        #pragma unroll
        for (int r = 0; r < 8; ++r)
            ((u32x4*)sB)[(16 + r * 4 + w) * 64 + lane] = stgB[r];
        __syncthreads();
        if (tid == 0) stg_cv_u32(FLG(320 + grp * 32 + ub), Qb + t);   // consumed h1[t-1]
        #pragma unroll
        for (int ks = NKSA; ks < NKS; ++ks)
            #pragma unroll
            for (int c = 0; c < 2; ++c)
                acc[c] = __builtin_amdgcn_mfma_f32_16x16x32_bf16(
                    aF[ks], sB[(ks * 2 + c) * 64 + lane], acc[c], 0, 0, 0);

        // ---- activation; pack h into sH
        #pragma unroll
        for (int c = 0; c < 2; ++c) {
            const float gi = acc[c][0], gf = acc[c][1];
            const float gg = acc[c][2], go = acc[c][3];
            const float cn_ = sigf(gf) * cst[c] + sigf(gi) * tanh_fast(gg);
            const float hv  = sigf(go) * tanh_fast(cn_);
            cst[c] = cn_;
            sH[((c * 2 + (w >> 1)) * 16 + lo) * 8 + (w & 1) * 4 + hi] = f2bf(hv);
            if (t == TT - 1) {
                const int j = jbase + hi, b = (ctbase + c) * 16 + lo;
                const size_t base = (size_t)TT * BB * DOUT;
                out[base + (size_t)b * HH + j] = hv;
                out[base + (size_t)2 * BB * HH + (size_t)b * HH + j] = cn_;
            }
        }

        // ---- deferred back-pressure (slot t&3 free); trailing sync publishes sH
        {
            const unsigned* wp = g_flg; unsigned wt = 0; int wa = 0;
            if (t >= 4) {
                if (w == 1) { wp = FLG(192 + (grp * 2 + (lane >> 5)) * 32 + (lane & 31));
                              wt = Qb + t - 3; wa = 1; }
                else if (w == 2 && lane < 32) { wp = FLG(320 + grp * 32 + lane);
                                                wt = Qb + t - 3; wa = 1; }
            }
            waitpoll(wp, wt, wa, tid);
        }

        // ---- wave0: wide 16B ring stores, drain, post ready
        u32x4* ringW = (u32x4*)g_h1f[t & 3];
        if (tid < 64) {
            const int c = tid >> 5, r = tid & 31, hi2 = r >> 4, lo2 = r & 15;
            const int f = ((ub >> 1) * 4 + ctbase + c) * 64 + ((ub & 1) * 2 + hi2) * 16 + lo2;
            stg_cv16(ringW + f, *(const u32x4*)&sH[((c * 2 + hi2) * 16 + lo2) * 8]);
        }
        wait_vm0();
        if (tid == 0) stg_cv_u32(FLG(0 + grp * 32 + ub), Qb + t + 1);
    }
}

// ---------------- L1: 128 WGs (ct=grp 0..3, ub2 0..31); wave = 4 units, 1 quadrant.
// NEW: wave-specialized overlap — after gate-A, waves 1-3 stage A while wave 0
// polls the critical h2[t-1] flags; one barrier joins them.
__device__ void run_l1(int lwg, int tid,
                       const float* __restrict__ wih, const float* __restrict__ whh,
                       const float* __restrict__ bih, const float* __restrict__ bhh,
                       float* __restrict__ out, unsigned Q, bf16x8* sB, short* sH)
{
    constexpr int NKSA = 16, NKS = 32;
    const int lane = tid & 63, lo = lane & 15, hi = lane >> 4;
    const int w = tid >> 6;
    const int grp = lwg & 3, ub = lwg >> 2;
    const int jbase = (ub * 4 + w) * 4;
    const int grow = (lo & 3) * HH + jbase + (lo >> 2);

    bf16x8 aF[NKS];
    #pragma unroll
    for (int ks = 0; ks < NKS; ++ks) {
        const float* wr = (ks < NKSA) ? wih + (size_t)grow * HH + ks * 32 + hi * 8
                                      : whh + (size_t)grow * HH + (ks - NKSA) * 32 + hi * 8;
        const float4* p = (const float4*)wr;
        aF[ks] = pack8(p[0], p[1]);
    }
    f32x4 biasv;
    #pragma unroll
    for (int r = 0; r < 4; ++r)
        biasv[r] = bih[r * HH + jbase + hi] + bhh[r * HH + jbase + hi];

    const unsigned Qb = Q * 2048u;
    float cst = 0.f;

    for (int t = 0; t < TT; ++t) {
        const bf16x8* srcA = g_h1f[t & 3];
        const bf16x8* srcB = (t == 0) ? g_h2z : g_h2f[(t - 1) & 3];

        // ---- gate A: h1[t] ready (w0; trailing sync fences sB/sH reuse)
        {
            const unsigned* wp = g_flg; unsigned wt = 0; int wa = 0;
            if (w == 0 && lane < 32) { wp = FLG(0 + (grp >> 1) * 32 + lane);
                                       wt = Qb + t + 1; wa = 1; }
            waitpoll(wp, wt, wa, tid);
        }

        // ---- OVERLAP: waves 1-3 stage the 16 A-rows; wave 0 polls h2[t-1]
        if (w == 0) {
            if (t >= 1) {
                const unsigned* p = FLG(64 + grp * 32 + lane);
                const unsigned tgt = Qb + t;
                for (;;) {
                    unsigned v = 0xFFFFFFFFu;
                    if (lane < 32)
                        asm volatile("global_load_dword %0, %1, off sc0 sc1\n\t"
                                     "s_waitcnt vmcnt(0)"
                                     : "=&v"(v) : "v"(p) : "memory");
                    if (__all(v >= tgt)) break;
                    __builtin_amdgcn_s_sleep(1);
                }
            }
        } else {
            // rows ri = r*3 + (w-1), r<6, ri<16: covers 0..15 exactly once
            u32x4 sa[6];
            #pragma unroll
            for (int r = 0; r < 6; ++r) {
                const int ri = r * 3 + (w - 1);
                if (ri < 16) sa[r] = ldg_cv16(&srcA[(ri * 4 + grp) * 64 + lane]);
            }
            wait_vm0();
            #pragma unroll
            for (int r = 0; r < 6; ++r) {
                const int ri = r * 3 + (w - 1);
                if (ri < 16) ((u32x4*)sB)[ri * 64 + lane] = sa[r];
            }
        }
        __syncthreads();   // A staged AND h2 detected
        if (tid == 0) stg_cv_u32(FLG(192 + grp * 32 + ub), Qb + t + 1);  // consumed h1[t]

        // ---- B loads (all waves) issued first, hidden under A-MFMAs
        u32x4 sb[4];
        #pragma unroll
        for (int r = 0; r < 4; ++r) {
            const int ks = r * 4 + w;
            sb[r] = ldg_cv16(&srcB[(ks * 4 + grp) * 64 + lane]);
        }
        f32x4 acc = biasv;
        #pragma unroll
        for (int ks = 0; ks < NKSA; ++ks)
            acc = __builtin_amdgcn_mfma_f32_16x16x32_bf16(
                aF[ks], sB[ks * 64 + lane], acc, 0, 0, 0);
        wait_vm0();
        #pragma unroll
        for (int r = 0; r < 4; ++r)
            ((u32x4*)sB)[(16 + r * 4 + w) * 64 + lane] = sb[r];
        __syncthreads();
        if (tid == 0) stg_cv_u32(FLG(384 + grp * 32 + ub), Qb + t);  // consumed h2[t-1]
        #pragma unroll
        for (int ks = NKSA; ks < NKS; ++ks)
            acc = __builtin_amdgcn_mfma_f32_16x16x32_bf16(
                aF[ks], sB[ks * 64 + lane], acc, 0, 0, 0);

        // ---- activation + sH pack
        {
            const float gi = acc[0], gf = acc[1], gg = acc[2], go = acc[3];
            const float cn_ = sigf(gf) * cst + sigf(gi) * tanh_fast(gg);
            const float hv  = sigf(go) * tanh_fast(cn_);
            cst = cn_;
            sH[((w >> 1) * 16 + lo) * 8 + (w & 1) * 4 + hi] = f2bf(hv);
            if (t == TT - 1) {
                const int j = jbase + hi, b = grp * 16 + lo;
                const size_t base = (size_t)TT * BB * DOUT;
                out[base + (size_t)BB * HH + (size_t)b * HH + j] = hv;
                out[base + (size_t)3 * BB * HH + (size_t)b * HH + j] = cn_;
            }
        }

        // ---- deferred back-pressure (slot t&3 free); trailing sync publishes sH
        {
            const unsigned* wp = g_flg; unsigned wt = 0; int wa = 0;
            if (t >= 4 && w == 1) {
                if (lane < 32)      { wp = FLG(384 + grp * 32 + lane);
                                      wt = Qb + t - 3; wa = 1; }
                else if (lane < 36) { wp = FLG(512 + (grp >> 1) * 4 + (lane - 32));
                                      wt = Qb + t - 3; wa = 1; }
            }
            waitpoll(wp, wt, wa, tid);
        }

        // ---- wave0: 32 x 16B ring stores, drain, post ready
        u32x4* ringW = (u32x4*)g_h2f[t & 3];
        if (tid < 32) {
            const int hi2 = tid >> 4, lo2 = tid & 15;
            const int f = ((ub >> 1) * 4 + grp) * 64 + ((ub & 1) * 2 + hi2) * 16 + lo2;
            stg_cv16(ringW + f, *(const u32x4*)&sH[(hi2 * 16 + lo2) * 8]);
        }
        wait_vm0();
        if (tid == 0) stg_cv_u32(FLG(64 + grp * 32 + ub), Qb + t + 1);
    }
}

// ---------------- output projection: 8 WGs = (ob 0..3, cp 0..1); wave = 16 odims
__device__ void run_out(int lwg, int tid,
                        const float* __restrict__ wout, const float* __restrict__ bout,
                        float* __restrict__ out, unsigned Q, bf16x8* sB)
{
    constexpr int NKS = HH / 32;   // 16
    constexpr int NST = 8;         // 32 staged rows / 4 waves
    const int lane = tid & 63, lo = lane & 15, hi = lane >> 4;
    const int w = tid >> 6;
    const int cp = lwg & 1, ob = lwg >> 1;
    const int ctbase = cp * 2;
    const int obase = (ob * 4 + w) * 16;
    const unsigned Qb = Q * 2048u;

    bf16x8 aF[NKS];
    #pragma unroll
    for (int ks = 0; ks < NKS; ++ks) {
        const float4* p = (const float4*)(wout + (size_t)(obase + lo) * HH + ks * 32 + hi * 8);
        aF[ks] = pack8(p[0], p[1]);
    }
    f32x4 biasv;
    #pragma unroll
    for (int r = 0; r < 4; ++r) biasv[r] = bout[obase + hi * 4 + r];

    for (int t = 0; t < TT; ++t) {
        const unsigned* wp = g_flg; unsigned wt = 0; int wa = 0;
        if (w == 0) {
            wp = FLG(64 + (ctbase + (lane >> 5)) * 32 + (lane & 31));
            wt = Qb + t + 1; wa = 1;
        }
        waitpoll(wp, wt, wa, tid);

        const bf16x8* src = g_h2f[t & 3];
        u32x4 stg[NST];
        #pragma unroll
        for (int r = 0; r < NST; ++r) {
            const int ri = r * 4 + w;
            const int ks = ri >> 1, c = ri & 1;
            stg[r] = ldg_cv16(&src[(ks * 4 + ctbase + c) * 64 + lane]);
        }
        wait_vm0();
        #pragma unroll
        for (int r = 0; r < NST; ++r)
            ((u32x4*)sB)[(r * 4 + w) * 64 + lane] = stg[r];
        __syncthreads();
        if (tid == 0) stg_cv_u32(FLG(512 + cp * 4 + ob), Qb + t + 1);

        f32x4 acc[2] = {biasv, biasv};
        #pragma unroll
        for (int ks = 0; ks < NKS; ++ks)
            #pragma unroll
            for (int c = 0; c < 2; ++c)
                acc[c] = __builtin_amdgcn_mfma_f32_16x16x32_bf16(
                    aF[ks], sB[(ks * 2 + c) * 64 + lane], acc[c], 0, 0, 0);
        #pragma unroll
        for (int c = 0; c < 2; ++c)
            #pragma unroll
            for (int r = 0; r < 4; ++r) {
                const int b = (ctbase + c) * 16 + lo, o = obase + hi * 4 + r;
                out[(size_t)t * BB * DOUT + (size_t)b * DOUT + o] = acc[c][r];
            }
    }
}

extern "C" __global__ void __launch_bounds__(256, 1)
lstm2_fused(const float* __restrict__ x,
            const float* __restrict__ wih0, const float* __restrict__ whh0,
            const float* __restrict__ bih0, const float* __restrict__ bhh0,
            const float* __restrict__ wih1, const float* __restrict__ whh1,
            const float* __restrict__ bih1, const float* __restrict__ bhh1,
            const float* __restrict__ wout, const float* __restrict__ bout,
            float* __restrict__ out)
{
    __shared__ bf16x8 sB[3072];                         // 48KB staging
    __shared__ __align__(16) short sH[2 * 2 * 16 * 8];  // 1KB h-pack buffer

    const int tid = threadIdx.x, wg = blockIdx.x;
    const unsigned Q = __hip_atomic_load(&g_iter, __ATOMIC_RELAXED, __HIP_MEMORY_SCOPE_AGENT);

    if (wg < NWG_L0)
        run_l0(wg, tid, wih0, whh0, bih0, bhh0, out, Q, sB, sH);
    else if (wg < NWG_L0 + NWG_L1)
        run_l1(wg - NWG_L0, tid, wih1, whh1, bih1, bhh1, out, Q, sB, sH);
    else
        run_out(wg - NWG_L0 - NWG_L1, tid, wout, bout, out, Q, sB);

    if (wg == 0 && tid == 0)
        __hip_atomic_store(&g_iter, Q + 1, __ATOMIC_RELAXED, __HIP_MEMORY_SCOPE_AGENT);
}

extern "C" void kernel_launch(void* const* d_in, const int* in_sizes, int n_in,
                              void* d_out, int out_size, void* d_ws, size_t ws_size,
                              hipStream_t stream) {
    const float* x    = (const float*)d_in[0];
    const float* wih0 = (const float*)d_in[1];
    const float* whh0 = (const float*)d_in[2];
    const float* bih0 = (const float*)d_in[3];
    const float* bhh0 = (const float*)d_in[4];
    const float* wih1 = (const float*)d_in[5];
    const float* whh1 = (const float*)d_in[6];
    const float* bih1 = (const float*)d_in[7];
    const float* bhh1 = (const float*)d_in[8];
    const float* wout = (const float*)d_in[9];
    const float* bout = (const float*)d_in[10];
    float* out = (float*)d_out;

    hipLaunchKernelGGL(pack_x, dim3(TT), dim3(256), 0, stream, x);
    hipLaunchKernelGGL(lstm2_fused, dim3(NWG_TOT), dim3(256), 0, stream,
                       x, wih0, whh0, bih0, bhh0, wih1, whh1, bih1, bhh1,
                       wout, bout, out);
}

// Round 23
// 3741.375 us; speedup vs baseline: 1.3881x; 1.0194x over previous
//
#include <hip/hip_runtime.h>

#define TT   1024
#define BB   64
#define DIN  256
#define HH   512
#define DOUT 256

#define NWG_L0  64
#define NWG_L1  128
#define NWG_OUT 8
#define NWG_TOT 200

typedef short bf16x8 __attribute__((ext_vector_type(8)));
typedef float f32x4  __attribute__((ext_vector_type(4)));
typedef unsigned u32x4 __attribute__((ext_vector_type(4)));

// frag-ordered bf16 tensors: index f = ((ks*4 + ct)*64 + lane), element e
// value = M[k = ks*32 + (lane>>4)*8 + e][col = ct*16 + (lane&15)]
__device__ bf16x8 g_xf[TT * 2048];     // x packed (static, cached path)
__device__ bf16x8 g_h1f[4][4096];      // h1 ring, 4 slots (coherent-bypass path)
__device__ bf16x8 g_h2f[4][4096];      // h2 ring
__device__ bf16x8 g_h1z[4096];         // t=-1 zeros (never written)
__device__ bf16x8 g_h2z[4096];

// per-producer/per-consumer progress flags, one 64B line each, monotone values
// V = Q*2048 + t(+1) (never reset -> replay-safe). NO atomics. R14-proven layout:
//   fp1  [p(2)][ub(32)]   : 0   + p*32+ub    L0 posts h1[t] ready    (Qb+t+1)
//   fp2  [ct(4)][ub2(32)] : 64  + ct*32+ub2  L1 posts h2[t] ready    (Qb+t+1)
//   fc1L1[ct(4)][ub2(32)] : 192 + ct*32+ub2  L1 consumed h1[t]       (Qb+t+1)
//   fc1L0[p(2)][ub(32)]   : 320 + p*32+ub    L0 consumed h1[t-1]     (Qb+t)
//   fc2L1[ct(4)][ub2(32)] : 384 + ct*32+ub2  L1 consumed h2[t-1]     (Qb+t)
//   fc2OUT[cp(2)*4+ob(4)] : 512 + cp*4+ob    OUT consumed h2[t]      (Qb+t+1)
__device__ unsigned g_flg[520 * 16];
__device__ unsigned g_iter;

__device__ __forceinline__ unsigned* FLG(int idx) { return &g_flg[idx * 16]; }

// ---------- explicitly-coherent (IF-level) primitives: bypass L1+L2
__device__ __forceinline__ u32x4 ldg_cv16(const void* p) {
    u32x4 r;
    asm volatile("global_load_dwordx4 %0, %1, off sc0 sc1"
                 : "=&v"(r) : "v"(p) : "memory");
    return r;
}
__device__ __forceinline__ void stg_cv16(void* p, u32x4 v) {
    asm volatile("global_store_dwordx4 %0, %1, off sc0 sc1" :: "v"(p), "v"(v) : "memory");
}
__device__ __forceinline__ void stg_cv_u32(void* p, unsigned v) {
    asm volatile("global_store_dword %0, %1, off sc0 sc1" :: "v"(p), "v"(v) : "memory");
}
__device__ __forceinline__ void wait_vm0(void) {
    asm volatile("s_waitcnt vmcnt(0)" ::: "memory");
}

// ---------- lane-parallel flag wait (UNSIGNED compare; inactive lanes hold ~0)
__device__ __forceinline__ void waitpoll(const unsigned* p, unsigned tgt, int active, int tid) {
    for (;;) {
        unsigned v = 0xFFFFFFFFu;
        if (active)
            asm volatile("global_load_dword %0, %1, off sc0 sc1\n\t"
                         "s_waitcnt vmcnt(0)"
                         : "=&v"(v) : "v"(p) : "memory");
        if (__all(v >= tgt)) break;
        __builtin_amdgcn_s_sleep(1);
    }
    __syncthreads();
}

__device__ __forceinline__ float sigf(float v) { return 1.f / (1.f + __expf(-v)); }
__device__ __forceinline__ float tanh_fast(float v) { return 2.f / (1.f + __expf(-2.f * v)) - 1.f; }

__device__ __forceinline__ short f2bf(float f) {   // RNE float->bf16 bits
    unsigned u = __builtin_bit_cast(unsigned, f);
    unsigned r = (u + 0x7FFFu + ((u >> 16) & 1u)) >> 16;
    return (short)r;
}

__device__ __forceinline__ bf16x8 pack8(float4 v0, float4 v1) {
    bf16x8 r;
    r[0] = f2bf(v0.x); r[1] = f2bf(v0.y); r[2] = f2bf(v0.z); r[3] = f2bf(v0.w);
    r[4] = f2bf(v1.x); r[5] = f2bf(v1.y); r[6] = f2bf(v1.z); r[7] = f2bf(v1.w);
    return r;
}

// ---------------- pre-pass: pack x (fp32 [T][B][DIN]) into frag-ordered bf16
extern "C" __global__ void __launch_bounds__(256)
pack_x(const float* __restrict__ x) {
    const int t = blockIdx.x, tid = threadIdx.x;
    const float* xt = x + (size_t)t * BB * DIN;
    bf16x8* dst = g_xf + (size_t)t * 2048;
    #pragma unroll
    for (int u = 0; u < 8; ++u) {
        const int f = u * 256 + tid;
        const int lane_ = f & 63, ctks = f >> 6;
        const int ct = ctks & 3, ks = ctks >> 2;
        const int b  = ct * 16 + (lane_ & 15);
        const int kb = ks * 32 + (lane_ >> 4) * 8;
        const float4* s = (const float4*)(xt + b * DIN + kb);
        dst[f] = pack8(s[0], s[1]);
    }
}

// ---------------- LSTM layer, split-phase. WG = (ub, NCT quadrants); wave = 4 units.
// L=0: A-rows = x (cached, no wait), B-rows = h1[t-1]. L=1: A = h1[t], B = h2[t-1].
template<int L, int NCT>
__device__ void run_layer(int lwg, int tid,
                          const float* __restrict__ wih, const float* __restrict__ whh,
                          const float* __restrict__ bih, const float* __restrict__ bhh,
                          float* __restrict__ out, unsigned Q, bf16x8* sB, short* sH)
{
    constexpr int KINX = (L == 0) ? DIN : HH;
    constexpr int NKSA = KINX / 32;          // A frag-rows per ct (8 or 16)
    constexpr int NKS  = NKSA + HH / 32;     // total (24 or 32)
    constexpr int NSTA = NKSA * NCT / 4;     // A rows staged per wave (4)
    constexpr int NSTB = (HH / 32) * NCT / 4;// B rows staged per wave (8 or 4)

    const int lane = tid & 63, lo = lane & 15, hi = lane >> 4;
    const int w      = tid >> 6;
    const int ctbase = (NCT == 2) ? (lwg & 1) * 2 : (lwg & 3);
    const int grp    = (NCT == 2) ? (lwg & 1) : (lwg & 3);        // p or ct
    const int ub     = (NCT == 2) ? (lwg >> 1) : (lwg >> 2);      // 0..31
    const int wv     = ub * 4 + w;
    const int jbase  = wv * 4;
    const int grow   = (lo & 3) * HH + jbase + (lo >> 2);  // gate-major A-row for lane lo

    // --- weights as bf16 A-fragments in registers (loaded once, cached)
    bf16x8 aF[NKS];
    #pragma unroll
    for (int ks = 0; ks < NKS; ++ks) {
        const float* wr;
        if (ks < NKSA) wr = wih + (size_t)grow * KINX + ks * 32 + hi * 8;
        else           wr = whh + (size_t)grow * HH + (ks - NKSA) * 32 + hi * 8;
        const float4* p = (const float4*)wr;
        aF[ks] = pack8(p[0], p[1]);
    }

    f32x4 biasv;
    #pragma unroll
    for (int r = 0; r < 4; ++r)
        biasv[r] = bih[r * HH + jbase + hi] + bhh[r * HH + jbase + hi];

    const unsigned Qb = Q * 2048u;
    float cst[NCT];
    #pragma unroll
    for (int c = 0; c < NCT; ++c) cst[c] = 0.f;

    for (int t = 0; t < TT; ++t) {
        const bf16x8* srcA = (L == 0) ? (g_xf + (size_t)t * 2048) : g_h1f[t & 3];
        const bf16x8* srcB = (L == 0) ? ((t == 0) ? g_h1z : g_h1f[(t - 1) & 3])
                                      : ((t == 0) ? g_h2z : g_h2f[(t - 1) & 3]);

        // ---- Phase A gate (L1 only): h1[t] ready
        if (L == 1) {
            const unsigned* wp = g_flg; unsigned wt = 0; int wa = 0;
            if (w == 0 && lane < 32) { wp = FLG(0 + (grp >> 1) * 32 + lane);
                                       wt = Qb + t + 1; wa = 1; }
            waitpoll(wp, wt, wa, tid);
        }

        // ---- Phase A stage: rows [0 .. NKSA*NCT)
        u32x4 stgA[NSTA];
        #pragma unroll
        for (int r = 0; r < NSTA; ++r) {
            const int ri = r * 4 + w, ks = ri / NCT, c = ri % NCT;
            const bf16x8* src = &srcA[(ks * 4 + ctbase + c) * 64 + lane];
            if (L == 0) stgA[r] = *(const u32x4*)src;   // cached x
            else        stgA[r] = ldg_cv16(src);        // bypass h1
        }
        wait_vm0();
        #pragma unroll
        for (int r = 0; r < NSTA; ++r)
            ((u32x4*)sB)[(r * 4 + w) * 64 + lane] = stgA[r];

        // ---- recurrent gate: B operand ready (trailing sync also publishes A in LDS)
        {
            const unsigned* wp = g_flg; unsigned wt = 0; int wa = 0;
            if (w == 0 && lane < 32 && t >= 1) {
                wp = (L == 0) ? FLG(0 + grp * 32 + lane) : FLG(64 + grp * 32 + lane);
                wt = Qb + t; wa = 1;
            }
            waitpoll(wp, wt, wa, tid);
        }
        // consumed-post for A (L1: h1[t] now safe in LDS)
        if (L == 1 && tid == 0) stg_cv_u32(FLG(192 + grp * 32 + ub), Qb + t + 1);

        // ---- Phase B: issue recurrent loads, overlap partial MFMA over A rows
        u32x4 stgB[NSTB];
        #pragma unroll
        for (int r = 0; r < NSTB; ++r) {
            const int ri = r * 4 + w, ks = ri / NCT, c = ri % NCT;
            stgB[r] = ldg_cv16(&srcB[(ks * 4 + ctbase + c) * 64 + lane]);
        }
        f32x4 acc[NCT];
        #pragma unroll
        for (int c = 0; c < NCT; ++c) acc[c] = biasv;
        #pragma unroll
        for (int ks = 0; ks < NKSA; ++ks)
            #pragma unroll
            for (int c = 0; c < NCT; ++c)
                acc[c] = __builtin_amdgcn_mfma_f32_16x16x32_bf16(
                    aF[ks], sB[(ks * NCT + c) * 64 + lane], acc[c], 0, 0, 0);
        wait_vm0();
        #pragma unroll
        for (int r = 0; r < NSTB; ++r)
            ((u32x4*)sB)[(NKSA * NCT + r * 4 + w) * 64 + lane] = stgB[r];
        __syncthreads();
        // consumed-post for B
        if (tid == 0) {
            if (L == 0) stg_cv_u32(FLG(320 + grp * 32 + ub), Qb + t);
            else        stg_cv_u32(FLG(384 + grp * 32 + ub), Qb + t);
        }
        #pragma unroll
        for (int ks = NKSA; ks < NKS; ++ks)
            #pragma unroll
            for (int c = 0; c < NCT; ++c)
                acc[c] = __builtin_amdgcn_mfma_f32_16x16x32_bf16(
                    aF[ks], sB[(ks * NCT + c) * 64 + lane], acc[c], 0, 0, 0);

        // ---- activation; pack h into sH (frag-ordered: e=(w&1)*4+hi, hi2=w>>1)
        #pragma unroll
        for (int c = 0; c < NCT; ++c) {
            const float gi = acc[c][0], gf = acc[c][1];
            const float gg = acc[c][2], go = acc[c][3];
            const float cn_ = sigf(gf) * cst[c] + sigf(gi) * tanh_fast(gg);
            const float hv  = sigf(go) * tanh_fast(cn_);
            cst[c] = cn_;
            sH[((c * 2 + (w >> 1)) * 16 + lo) * 8 + (w & 1) * 4 + hi] = f2bf(hv);
            if (t == TT - 1) {
                const int j = jbase + hi, b = (ctbase + c) * 16 + lo;
                const size_t base = (size_t)TT * BB * DOUT;
                out[base + (size_t)L * BB * HH + (size_t)b * HH + j] = hv;
                out[base + (size_t)2 * BB * HH + (size_t)L * BB * HH + (size_t)b * HH + j] = cn_;
            }
        }

        // ---- deferred back-pressure: slot (t&3) free? (R14 flags/targets, proven)
        {
            const unsigned* wp = g_flg; unsigned wt = 0; int wa = 0;
            if (t >= 4) {
                if (L == 0) {
                    if (w == 1) { wp = FLG(192 + (grp * 2 + (lane >> 5)) * 32 + (lane & 31));
                                  wt = Qb + t - 3; wa = 1; }
                    else if (w == 2 && lane < 32) { wp = FLG(320 + grp * 32 + lane);
                                                    wt = Qb + t - 3; wa = 1; }
                } else {
                    if (w == 1) {
                        if (lane < 32)      { wp = FLG(384 + grp * 32 + lane);
                                              wt = Qb + t - 3; wa = 1; }
                        else if (lane < 36) { wp = FLG(512 + (grp >> 1) * 4 + (lane - 32));
                                              wt = Qb + t - 3; wa = 1; }
                    }
                }
            }
            waitpoll(wp, wt, wa, tid);   // trailing sync also publishes sH
        }

        // ---- wave0: wide 16B ring stores from sH, then post ready
        u32x4* ringW = (u32x4*)((L == 0) ? g_h1f[t & 3] : g_h2f[t & 3]);
        if (tid < 32 * NCT) {
            const int c = tid >> 5, r = tid & 31, hi2 = r >> 4, lo2 = r & 15;
            const int f = ((ub >> 1) * 4 + ctbase + c) * 64 + ((ub & 1) * 2 + hi2) * 16 + lo2;
            stg_cv16(ringW + f, *(const u32x4*)&sH[((c * 2 + hi2) * 16 + lo2) * 8]);
        }
        wait_vm0();   // wave0's stores at coherence point (other waves: no-op)
        if (tid == 0) {
            if (L == 0) stg_cv_u32(FLG(0 + grp * 32 + ub), Qb + t + 1);
            else        stg_cv_u32(FLG(64 + grp * 32 + ub), Qb + t + 1);
        }
        // no trailing barrier needed: only wave0 touched sH/ring; next-step syncs cover reuse
    }
}

// ---------------- output projection: 8 WGs = (ob 0..3, cp 0..1); wave = 16 odims
__device__ void run_out(int lwg, int tid,
                        const float* __restrict__ wout, const float* __restrict__ bout,
                        float* __restrict__ out, unsigned Q, bf16x8* sB)
{
    constexpr int NKS  = HH / 32;   // 16 frag-rows
    constexpr int NST  = 8;         // 32 staged rows / 4 waves
    const int lane = tid & 63, lo = lane & 15, hi = lane >> 4;
    const int w = tid >> 6;
    const int cp = lwg & 1, ob = lwg >> 1;
    const int ctbase = cp * 2;
    const int obase = (ob * 4 + w) * 16;
    const unsigned Qb = Q * 2048u;

    bf16x8 aF[NKS];
    #pragma unroll
    for (int ks = 0; ks < NKS; ++ks) {
        const float4* p = (const float4*)(wout + (size_t)(obase + lo) * HH + ks * 32 + hi * 8);
        aF[ks] = pack8(p[0], p[1]);
    }
    f32x4 biasv;
    #pragma unroll
    for (int r = 0; r < 4; ++r) biasv[r] = bout[obase + hi * 4 + r];

    for (int t = 0; t < TT; ++t) {
        const unsigned* wp = g_flg; unsigned wt = 0; int wa = 0;
        if (w == 0) {   // h2[t] ready: quadrants 2cp (lanes 0-31), 2cp+1 (lanes 32-63)
            wp = FLG(64 + (ctbase + (lane >> 5)) * 32 + (lane & 31));
            wt = Qb + t + 1; wa = 1;
        }
        waitpoll(wp, wt, wa, tid);

        const bf16x8* src = g_h2f[t & 3];
        u32x4 stg[NST];
        #pragma unroll
        for (int r = 0; r < NST; ++r) {
            const int ri = r * 4 + w;
            const int ks = ri >> 1, c = ri & 1;
            stg[r] = ldg_cv16(&src[(ks * 4 + ctbase + c) * 64 + lane]);
        }
        wait_vm0();
        #pragma unroll
        for (int r = 0; r < NST; ++r)
            ((u32x4*)sB)[(r * 4 + w) * 64 + lane] = stg[r];
        __syncthreads();
        if (tid == 0) stg_cv_u32(FLG(512 + cp * 4 + ob), Qb + t + 1);

        f32x4 acc[2] = {biasv, biasv};
        #pragma unroll
        for (int ks = 0; ks < NKS; ++ks)
            #pragma unroll
            for (int c = 0; c < 2; ++c)
                acc[c] = __builtin_amdgcn_mfma_f32_16x16x32_bf16(
                    aF[ks], sB[(ks * 2 + c) * 64 + lane], acc[c], 0, 0, 0);
        #pragma unroll
        for (int c = 0; c < 2; ++c)
            #pragma unroll
            for (int r = 0; r < 4; ++r) {
                const int b = (ctbase + c) * 16 + lo, o = obase + hi * 4 + r;
                out[(size_t)t * BB * DOUT + (size_t)b * DOUT + o] = acc[c][r];
            }
    }
}

extern "C" __global__ void __launch_bounds__(256, 1)
lstm2_fused(const float* __restrict__ x,
            const float* __restrict__ wih0, const float* __restrict__ whh0,
            const float* __restrict__ bih0, const float* __restrict__ bhh0,
            const float* __restrict__ wih1, const float* __restrict__ whh1,
            const float* __restrict__ bih1, const float* __restrict__ bhh1,
            const float* __restrict__ wout, const float* __restrict__ bout,
            float* __restrict__ out)
{
    __shared__ bf16x8 sB[3072];                      // 48KB staging
    __shared__ __align__(16) short sH[2 * 2 * 16 * 8];  // 1KB h-pack buffer

    const int tid = threadIdx.x, wg = blockIdx.x;
    const unsigned Q = __hip_atomic_load(&g_iter, __ATOMIC_RELAXED, __HIP_MEMORY_SCOPE_AGENT);

    if (wg < NWG_L0)
        run_layer<0, 2>(wg, tid, wih0, whh0, bih0, bhh0, out, Q, sB, sH);
    else if (wg < NWG_L0 + NWG_L1)
        run_layer<1, 1>(wg - NWG_L0, tid, wih1, whh1, bih1, bhh1, out, Q, sB, sH);
    else
        run_out(wg - NWG_L0 - NWG_L1, tid, wout, bout, out, Q, sB);

    if (wg == 0 && tid == 0)
        __hip_atomic_store(&g_iter, Q + 1, __ATOMIC_RELAXED, __HIP_MEMORY_SCOPE_AGENT);
}

extern "C" void kernel_launch(void* const* d_in, const int* in_sizes, int n_in,
                              void* d_out, int out_size, void* d_ws, size_t ws_size,
                              hipStream_t stream) {
    const float* x    = (const float*)d_in[0];
    const float* wih0 = (const float*)d_in[1];
    const float* whh0 = (const float*)d_in[2];
    const float* bih0 = (const float*)d_in[3];
    const float* bhh0 = (const float*)d_in[4];
    const float* wih1 = (const float*)d_in[5];
    const float* whh1 = (const float*)d_in[6];
    const float* bih1 = (const float*)d_in[7];
    const float* bhh1 = (const float*)d_in[8];
    const float* wout = (const float*)d_in[9];
    const float* bout = (const float*)d_in[10];
    float* out = (float*)d_out;

    hipLaunchKernelGGL(pack_x, dim3(TT), dim3(256), 0, stream, x);
    hipLaunchKernelGGL(lstm2_fused, dim3(NWG_TOT), dim3(256), 0, stream,
                       x, wih0, whh0, bih0, bhh0, wih1, whh1, bih1, bhh1,
                       wout, bout, out);
}